// Round 1
// baseline (64.678 us; speedup 1.0000x reference)
//
#include <hip/hip_runtime.h>

#define CH_PIX (512 * 512)

__global__ __launch_bounds__(768) void zero_out_k(unsigned int* out) {
    int i = threadIdx.x;
    if (i < 768) out[i] = 0u;
}

__global__ __launch_bounds__(256) void lbp_hist_k(const float* __restrict__ x,
                                                  unsigned int* __restrict__ gc) {
    const int chan  = blockIdx.y;            // 0..95  (b*3 + c)
    const int chunk = blockIdx.x;            // 0..63, 4096 px each
    const float* __restrict__ img = x + (size_t)chan * CH_PIX;

    __shared__ unsigned int h[8 * 64];
    for (int i = threadIdx.x; i < 512; i += 256) h[i] = 0u;
    __syncthreads();

    const int lane = threadIdx.x & 63;

    // weights: s = sin(pi/4) in double, products in double, rounded to f32
    constexpr double Sd = 0.7071067811865476;
    constexpr double Td = 1.0 - Sd;
    const float wSS = (float)(Sd * Sd);
    const float wST = (float)(Sd * Td);
    const float wTT = (float)(Td * Td);
    const float invw = (float)(8.0 / 255.0);

    const int base = chunk * 4096;
    for (int t = threadIdx.x; t < 4096; t += 256) {
        const int p = base + t;
        const int y = p >> 9, xx = p & 511;
        const bool y0 = y > 0, y1 = y < 511, x0 = xx > 0, x1 = xx < 511;

        // clamped-address loads (always in-bounds), then select 0 for padding
        auto ld = [&](int off, bool ok) -> float {
            int q = p + off;
            q = q < 0 ? 0 : (q >= CH_PIX ? CH_PIX - 1 : q);
            float v = img[q];
            return ok ? v : 0.0f;
        };
        const float c  = img[p];
        const float n  = ld(-512, y0);
        const float s_ = ld( 512, y1);
        const float w  = ld(  -1, x0);
        const float e  = ld(   1, x1);
        const float nw = ld(-513, y0 && x0);
        const float ne = ld(-511, y0 && x1);
        const float sw = ld( 511, y1 && x0);
        const float se = ld( 513, y1 && x1);

        // bilinear diagonal samples, same weight placement + add order as ref
        const float nb1 = ((wST * n  + wSS * ne) + wTT * c ) + wST * e;   // (-s,+s)
        const float nb3 = ((wSS * nw + wST * n ) + wST * w ) + wTT * c;   // (-s,-s)
        const float nb5 = ((wST * w  + wTT * c ) + wSS * sw) + wST * s_;  // (+s,-s)
        const float nb7 = ((wTT * c  + wST * e ) + wST * s_) + wSS * se;  // (+s,+s)

        int code = 0;
        code |= (e   - c >= 0.0f) ? 1   : 0;
        code |= (nb1 - c >= 0.0f) ? 2   : 0;
        code |= (n   - c >= 0.0f) ? 4   : 0;
        code |= (nb3 - c >= 0.0f) ? 8   : 0;
        code |= (w   - c >= 0.0f) ? 16  : 0;
        code |= (nb5 - c >= 0.0f) ? 32  : 0;
        code |= (s_  - c >= 0.0f) ? 64  : 0;
        code |= (nb7 - c >= 0.0f) ? 128 : 0;

        int b = (int)((float)code * invw);
        b = b > 7 ? 7 : b;
        atomicAdd(&h[b * 64 + lane], 1u);
    }
    __syncthreads();

    if (threadIdx.x < 8) {
        unsigned int s = 0;
        #pragma unroll
        for (int l = 0; l < 64; ++l) s += h[threadIdx.x * 64 + l];
        atomicAdd(&gc[chan * 8 + threadIdx.x], s);
    }
}

__global__ __launch_bounds__(768) void finalize_k(unsigned int* io) {
    int i = threadIdx.x;
    if (i < 768) {
        unsigned int u = io[i];
        ((float*)io)[i] = (float)u / 8355840.0f;   // counts / (H*W * width)
    }
}

extern "C" void kernel_launch(void* const* d_in, const int* in_sizes, int n_in,
                              void* d_out, int out_size, void* d_ws, size_t ws_size,
                              hipStream_t stream) {
    const float* x = (const float*)d_in[0];
    unsigned int* out = (unsigned int*)d_out;

    zero_out_k<<<1, 768, 0, stream>>>(out);
    dim3 grid(64, 96);
    lbp_hist_k<<<grid, 256, 0, stream>>>(x, out);
    finalize_k<<<1, 768, 0, stream>>>(out);
}

// Round 2
// 30.712 us; speedup vs baseline: 2.1059x; 2.1059x over previous
//
#include <hip/hip_runtime.h>

#define W 512
#define H 512
#define CH_PIX (W * H)
#define NCH 96

__global__ __launch_bounds__(768) void zero_out_k(unsigned int* out) {
    int i = threadIdx.x;
    if (i < 768) out[i] = 0u;
}

// Each block: one channel x one 32-row band (2 strips of 16 rows).
// Thread owns float4 group g (4 px wide), walks rows top->bottom, reusing the
// previous "down" row as the current "mid" row (registers, no re-load).
// Only bits 5..7 of the LBP code are needed: bin = code>>5 == floor(code*8/255).
__global__ __launch_bounds__(256) void lbp_main_k(const float* __restrict__ x,
                                                  unsigned int* __restrict__ gc) {
    const int chan = blockIdx.x;     // 0..95
    const int band = blockIdx.y;     // 0..16 (16 = bottom-row special band)
    const int tid  = threadIdx.x;
    const int g     = tid & 127;     // float4 group 0..127
    const int strip = tid >> 7;      // 0..1
    const int lane  = tid & 63;

    __shared__ unsigned int h[8 * 64];
    for (int i = tid; i < 512; i += 256) h[i] = 0u;
    __syncthreads();

    constexpr double Sd = 0.7071067811865476;
    constexpr double Td = 1.0 - Sd;
    const float wSS = (float)(Sd * Sd);
    const float wST = (float)(Sd * Td);
    const float wTT = (float)(Td * Td);

    const int  col  = g << 2;
    const bool g0   = (g == 0), g127 = (g == 127);

    if (band < 16) {
        const int y0   = band * 32 + strip * 16;
        const int yend = min(y0 + 16, 511);   // rows with a valid row below

        int idx = chan * CH_PIX + y0 * W + col;
        float4 m4 = *(const float4*)(x + idx);
        float  mL = g0   ? 0.0f : x[idx - 1];
        float  mR = g127 ? 0.0f : x[idx + 4];

        for (int y = y0; y < yend; ++y) {
            const int idxD = idx + W;
            float4 d4 = *(const float4*)(x + idxD);
            float  dL = g0   ? 0.0f : x[idxD - 1];
            float  dR = g127 ? 0.0f : x[idxD + 4];

            const float cs[4]  = {m4.x, m4.y, m4.z, m4.w};
            const float es[4]  = {m4.y, m4.z, m4.w, mR};
            const float ws[4]  = {mL,   m4.x, m4.y, m4.z};
            const float ss[4]  = {d4.x, d4.y, d4.z, d4.w};
            const float sws[4] = {dL,   d4.x, d4.y, d4.z};
            const float ses[4] = {d4.y, d4.z, d4.w, dR};

            #pragma unroll
            for (int i = 0; i < 4; ++i) {
                const float c  = cs[i];
                const float tc = wTT * c;
                const float ts = wST * ss[i];
                const float nb5 = ((wST * ws[i] + tc) + wSS * sws[i]) + ts;
                const float nb7 = ((tc + wST * es[i]) + ts) + wSS * ses[i];
                const int bin = (nb5 >= c ? 1 : 0) | (ss[i] >= c ? 2 : 0) |
                                (nb7 >= c ? 4 : 0);
                atomicAdd(&h[(bin << 6) + lane], 1u);
            }
            m4 = d4; mL = dL; mR = dR;
            idx = idxD;
        }
    } else if (strip == 0) {
        // bottom row y = 511: s, sw, se are zero-padded
        const int idx = chan * CH_PIX + 511 * W + col;
        float4 m4 = *(const float4*)(x + idx);
        float  mL = g0   ? 0.0f : x[idx - 1];
        float  mR = g127 ? 0.0f : x[idx + 4];

        const float cs[4] = {m4.x, m4.y, m4.z, m4.w};
        const float es[4] = {m4.y, m4.z, m4.w, mR};
        const float ws[4] = {mL,   m4.x, m4.y, m4.z};

        #pragma unroll
        for (int i = 0; i < 4; ++i) {
            const float c  = cs[i];
            const float tc = wTT * c;
            const float ts = wST * 0.0f;
            const float nb5 = ((wST * ws[i] + tc) + wSS * 0.0f) + ts;
            const float nb7 = ((tc + wST * es[i]) + ts) + wSS * 0.0f;
            const int bin = (nb5 >= c ? 1 : 0) | (0.0f >= c ? 2 : 0) |
                            (nb7 >= c ? 4 : 0);
            atomicAdd(&h[(bin << 6) + lane], 1u);
        }
    }
    __syncthreads();

    if (tid < 8) {
        unsigned int s = 0;
        #pragma unroll
        for (int l = 0; l < 64; ++l) s += h[(tid << 6) + l];
        atomicAdd(&gc[chan * 8 + tid], s);
    }
}

__global__ __launch_bounds__(768) void finalize_k(unsigned int* io) {
    int i = threadIdx.x;
    if (i < 768) {
        unsigned int u = io[i];
        ((float*)io)[i] = (float)u / 8355840.0f;   // counts / (H*W * 255/8)
    }
}

extern "C" void kernel_launch(void* const* d_in, const int* in_sizes, int n_in,
                              void* d_out, int out_size, void* d_ws, size_t ws_size,
                              hipStream_t stream) {
    const float* x = (const float*)d_in[0];
    unsigned int* out = (unsigned int*)d_out;

    zero_out_k<<<1, 768, 0, stream>>>(out);
    dim3 grid(NCH, 17);
    lbp_main_k<<<grid, 256, 0, stream>>>(x, out);
    finalize_k<<<1, 768, 0, stream>>>(out);
}

// Round 3
// 30.188 us; speedup vs baseline: 2.1425x; 1.0174x over previous
//
#include <hip/hip_runtime.h>

#define W 512
#define H 512
#define CH_PIX (W * H)
#define NCH 96

__global__ __launch_bounds__(768) void zero_out_k(unsigned int* out) {
    int i = threadIdx.x;
    if (i < 768) out[i] = 0u;
}

// Block: one channel x one 32-row band (2 strips of 16 rows, 2 waves each).
// Thread owns a float4 group (4 px wide), walks rows top->bottom, rotating the
// "down" row into "mid" (register reuse, each row loaded once per strip).
// bin = LBP code >> 5 (proven == floor(code*8/255)), so only bits 5..7 matter:
// s (down), nb5 (down-left bilinear), nb7 (down-right bilinear).
// Histogram: 8 byte-counters packed in 2 u32 registers per thread; merged to
// LDS once per thread at the end (no per-pixel atomics).
__global__ __launch_bounds__(256) void lbp_main_k(const float* __restrict__ x,
                                                  unsigned int* __restrict__ gc) {
    const int chan = blockIdx.x;     // 0..95
    const int band = blockIdx.y;     // 0..16 (16 = bottom-row special band)
    const int tid  = threadIdx.x;
    const int g     = tid & 127;     // float4 group 0..127
    const int strip = tid >> 7;      // 0..1
    const int lane  = tid & 63;

    __shared__ unsigned int h[8 * 64];
    for (int i = tid; i < 512; i += 256) h[i] = 0u;
    __syncthreads();

    constexpr double Sd = 0.7071067811865476;
    constexpr double Td = 1.0 - Sd;
    const float wSS = (float)(Sd * Sd);
    const float wST = (float)(Sd * Td);
    const float wTT = (float)(Td * Td);

    const int  col  = g << 2;
    const bool g0   = (g == 0), g127 = (g == 127);

    unsigned int cLo = 0u, cHi = 0u;   // bins 0..3 / 4..7 as packed bytes

    if (band < 16) {
        const int y0   = band * 32 + strip * 16;
        const int yend = min(y0 + 16, 511);   // rows with a valid row below

        int idx = chan * CH_PIX + y0 * W + col;
        float4 m4 = *(const float4*)(x + idx);
        float  mL = g0   ? 0.0f : x[idx - 1];
        float  mR = g127 ? 0.0f : x[idx + 4];

        for (int y = y0; y < yend; ++y) {
            const int idxD = idx + W;
            float4 d4 = *(const float4*)(x + idxD);
            float  dL = g0   ? 0.0f : x[idxD - 1];
            float  dR = g127 ? 0.0f : x[idxD + 4];

            const float cs[4]  = {m4.x, m4.y, m4.z, m4.w};
            const float es[4]  = {m4.y, m4.z, m4.w, mR};
            const float ws[4]  = {mL,   m4.x, m4.y, m4.z};
            const float ss[4]  = {d4.x, d4.y, d4.z, d4.w};
            const float sws[4] = {dL,   d4.x, d4.y, d4.z};
            const float ses[4] = {d4.y, d4.z, d4.w, dR};

            #pragma unroll
            for (int i = 0; i < 4; ++i) {
                const float c  = cs[i];
                const float tc = wTT * c;
                const float ts = wST * ss[i];
                const float nb5 = ((wST * ws[i] + tc) + wSS * sws[i]) + ts;
                const float nb7 = ((tc + wST * es[i]) + ts) + wSS * ses[i];
                const bool p0 = (nb5   >= c);
                const bool p1 = (ss[i] >= c);
                const bool p2 = (nb7   >= c);
                const unsigned int amt = (p0 ? 8u : 0u) | (p1 ? 16u : 0u);
                const unsigned int inc = 1u << amt;
                cLo += p2 ? 0u : inc;
                cHi += p2 ? inc : 0u;
            }
            m4 = d4; mL = dL; mR = dR;
            idx = idxD;
        }
    } else if (strip == 0) {
        // bottom row y = 511: s, sw, se are zero-padded
        const int idx = chan * CH_PIX + 511 * W + col;
        float4 m4 = *(const float4*)(x + idx);
        float  mL = g0   ? 0.0f : x[idx - 1];
        float  mR = g127 ? 0.0f : x[idx + 4];

        const float cs[4] = {m4.x, m4.y, m4.z, m4.w};
        const float es[4] = {m4.y, m4.z, m4.w, mR};
        const float ws[4] = {mL,   m4.x, m4.y, m4.z};

        #pragma unroll
        for (int i = 0; i < 4; ++i) {
            const float c  = cs[i];
            const float tc = wTT * c;
            const float nb5 = ((wST * ws[i] + tc) + wSS * 0.0f) + wST * 0.0f;
            const float nb7 = ((tc + wST * es[i]) + wST * 0.0f) + wSS * 0.0f;
            const bool p0 = (nb5  >= c);
            const bool p1 = (0.0f >= c);
            const bool p2 = (nb7  >= c);
            const unsigned int amt = (p0 ? 8u : 0u) | (p1 ? 16u : 0u);
            const unsigned int inc = 1u << amt;
            cLo += p2 ? 0u : inc;
            cHi += p2 ? inc : 0u;
        }
    }

    // merge packed byte counters into the LDS histogram (8 DS atomics/thread)
    #pragma unroll
    for (int b = 0; b < 4; ++b) {
        atomicAdd(&h[(b     << 6) + lane], (cLo >> (b * 8)) & 0xffu);
        atomicAdd(&h[((b+4) << 6) + lane], (cHi >> (b * 8)) & 0xffu);
    }
    __syncthreads();

    if (tid < 8) {
        unsigned int s = 0;
        #pragma unroll
        for (int l = 0; l < 64; ++l) s += h[(tid << 6) + l];
        atomicAdd(&gc[chan * 8 + tid], s);
    }
}

__global__ __launch_bounds__(768) void finalize_k(unsigned int* io) {
    int i = threadIdx.x;
    if (i < 768) {
        unsigned int u = io[i];
        ((float*)io)[i] = (float)u / 8355840.0f;   // counts / (H*W * 255/8)
    }
}

extern "C" void kernel_launch(void* const* d_in, const int* in_sizes, int n_in,
                              void* d_out, int out_size, void* d_ws, size_t ws_size,
                              hipStream_t stream) {
    const float* x = (const float*)d_in[0];
    unsigned int* out = (unsigned int*)d_out;

    zero_out_k<<<1, 768, 0, stream>>>(out);
    dim3 grid(NCH, 17);
    lbp_main_k<<<grid, 256, 0, stream>>>(x, out);
    finalize_k<<<1, 768, 0, stream>>>(out);
}

// Round 4
// 28.422 us; speedup vs baseline: 2.2756x; 1.0621x over previous
//
#include <hip/hip_runtime.h>

#define W 512
#define H 512
#define CH_PIX (W * H)

// Block: one channel x one 32-row band (2 strips of 16 rows; 2 waves each).
// All 17 rows of a strip are loaded up-front (fully unrolled, ~51 VMEM in
// flight per wave) then 16 rows computed from registers: no serial
// load->compute chain, deep memory pipelining.
// bin = LBP code >> 5 (proven == floor(code*8/255)): only bits 5..7 matter:
// s (down), nb5 (down-left bilinear), nb7 (down-right bilinear).
// Per-thread 8x8-bit packed counter in one u64; merged once at the end.
__global__ __launch_bounds__(256) void lbp_main_k(const float* __restrict__ x,
                                                  unsigned int* __restrict__ ws) {
    const int chan = blockIdx.x;     // 0..95
    const int band = blockIdx.y;     // 0..16 (16 = bottom-row special band)
    const int tid  = threadIdx.x;
    const int g     = tid & 127;     // float4 group 0..127
    const int strip = tid >> 7;      // 0..1
    const int lane  = tid & 63;

    __shared__ unsigned int h[8 * 64];
    for (int i = tid; i < 512; i += 256) h[i] = 0u;
    __syncthreads();

    constexpr double Sd = 0.7071067811865476;
    constexpr double Td = 1.0 - Sd;
    const float wSS = (float)(Sd * Sd);
    const float wST = (float)(Sd * Td);
    const float wTT = (float)(Td * Td);

    const int  col  = g << 2;
    const bool g0   = (g == 0), g127 = (g == 127);

    unsigned long long c64 = 0ull;   // 8 bins x 8-bit counters (max 64/strip)

    if (band < 16) {
        const int y0 = band * 32 + strip * 16;
        const int nr = (y0 == 496) ? 15 : 16;      // rows computed here
        const int base = chan * CH_PIX + y0 * W + col;

        float4 r4[17];
        float  rL[17], rR[17];
        #pragma unroll
        for (int k = 0; k < 17; ++k) {
            const int kk   = (y0 + k > 511) ? (511 - y0) : k;  // clamp (safe)
            const int ridx = base + kk * W;
            r4[k] = *(const float4*)(x + ridx);
            rL[k] = g0   ? 0.0f : x[ridx - 1];
            rR[k] = g127 ? 0.0f : x[ridx + 4];
        }

        #pragma unroll
        for (int k = 0; k < 16; ++k) {
            if (k < nr) {
                const float4 m4 = r4[k], d4 = r4[k + 1];
                const float mL = rL[k], mR = rR[k];
                const float dL = rL[k + 1], dR = rR[k + 1];

                const float cs[4]  = {m4.x, m4.y, m4.z, m4.w};
                const float es[4]  = {m4.y, m4.z, m4.w, mR};
                const float wsA[4] = {mL,   m4.x, m4.y, m4.z};
                const float ss[4]  = {d4.x, d4.y, d4.z, d4.w};
                const float sws[4] = {dL,   d4.x, d4.y, d4.z};
                const float ses[4] = {d4.y, d4.z, d4.w, dR};

                #pragma unroll
                for (int i = 0; i < 4; ++i) {
                    const float c  = cs[i];
                    const float tc = wTT * c;
                    const float ts = wST * ss[i];
                    const float nb5 = ((wST * wsA[i] + tc) + wSS * sws[i]) + ts;
                    const float nb7 = ((tc + wST * es[i]) + ts) + wSS * ses[i];
                    const unsigned int amt = (nb5   >= c ? 8u  : 0u)
                                           + (ss[i] >= c ? 16u : 0u)
                                           + (nb7   >= c ? 32u : 0u);
                    c64 += 1ull << amt;
                }
            }
        }
    } else if (strip == 0) {
        // bottom row y = 511: s, sw, se zero-padded
        const int idx = chan * CH_PIX + 511 * W + col;
        const float4 m4 = *(const float4*)(x + idx);
        const float mL = g0   ? 0.0f : x[idx - 1];
        const float mR = g127 ? 0.0f : x[idx + 4];

        const float cs[4]  = {m4.x, m4.y, m4.z, m4.w};
        const float es[4]  = {m4.y, m4.z, m4.w, mR};
        const float wsA[4] = {mL,   m4.x, m4.y, m4.z};

        #pragma unroll
        for (int i = 0; i < 4; ++i) {
            const float c  = cs[i];
            const float tc = wTT * c;
            const float nb5 = ((wST * wsA[i] + tc) + wSS * 0.0f) + wST * 0.0f;
            const float nb7 = ((tc + wST * es[i]) + wST * 0.0f) + wSS * 0.0f;
            const unsigned int amt = (nb5  >= c ? 8u  : 0u)
                                   + (0.0f >= c ? 16u : 0u)
                                   + (nb7  >= c ? 32u : 0u);
            c64 += 1ull << amt;
        }
    }

    // merge packed byte counters into LDS histogram (8 DS atomics/thread)
    const unsigned int lo = (unsigned int)c64;
    const unsigned int hi = (unsigned int)(c64 >> 32);
    #pragma unroll
    for (int b = 0; b < 4; ++b) {
        atomicAdd(&h[(b       << 6) + lane], (lo >> (b * 8)) & 0xffu);
        atomicAdd(&h[((b + 4) << 6) + lane], (hi >> (b * 8)) & 0xffu);
    }
    __syncthreads();

    if (tid < 8) {
        unsigned int s = 0;
        #pragma unroll
        for (int l = 0; l < 64; ++l) s += h[(tid << 6) + l];
        ws[(chan * 17 + band) * 8 + tid] = s;   // non-atomic partial per block
    }
}

__global__ __launch_bounds__(64) void finalize_k(const unsigned int* __restrict__ ws,
                                                 float* __restrict__ out) {
    const int gid = blockIdx.x * 64 + threadIdx.x;   // 0..767
    if (gid < 768) {
        const int chan = gid >> 3, bin = gid & 7;
        unsigned int s = 0;
        #pragma unroll
        for (int b = 0; b < 17; ++b) s += ws[(chan * 17 + b) * 8 + bin];
        out[gid] = (float)s / 8355840.0f;   // counts / (H*W * 255/8)
    }
}

extern "C" void kernel_launch(void* const* d_in, const int* in_sizes, int n_in,
                              void* d_out, int out_size, void* d_ws, size_t ws_size,
                              hipStream_t stream) {
    const float* x = (const float*)d_in[0];
    unsigned int* wsp = (unsigned int*)d_ws;
    float* out = (float*)d_out;

    dim3 grid(96, 17);
    lbp_main_k<<<grid, 256, 0, stream>>>(x, wsp);
    finalize_k<<<12, 64, 0, stream>>>(wsp, out);
}

// Round 5
// 26.997 us; speedup vs baseline: 2.3958x; 1.0528x over previous
//
#include <hip/hip_runtime.h>

#define W 512
#define H 512
#define CH_PIX (W * H)

// Lane-edge L/R neighbors via cross-lane shuffle; seam value hk patched in at
// the wave boundary (x=255/256), image edges get 0.
__device__ __forceinline__ float2 lr_for(float4 v, float hk, int half, int lane) {
    const float up = __shfl_up(v.w, 1, 64);    // lane-1's .w  -> left neighbor
    const float dn = __shfl_down(v.x, 1, 64);  // lane+1's .x  -> right neighbor
    const float eL = half ? hk : 0.0f;
    const float eR = half ? 0.0f : hk;
    float2 r;
    r.x = (lane == 0)  ? eL : up;
    r.y = (lane == 63) ? eR : dn;
    return r;
}

// Block: one channel x one 32-row band. 4 waves = 2 row-strips x 2 half-rows.
// Wave owns 16 rows x 256 px; lane owns one float4 column group and walks rows.
// Rows y0..y0+16 loaded as 17 float4s (fully unrolled, all in flight) plus ONE
// gather instruction for the 17 seam scalars. No divergent edge loads.
// bin = LBP code >> 5 (== floor(code*8/255)): only bits 5..7 matter:
// s (down), nb5 (down-left bilinear), nb7 (down-right bilinear).
// Per-thread 8x8-bit packed counters in one u64, merged once at the end.
__global__ __launch_bounds__(256) void lbp_main_k(const float* __restrict__ x,
                                                  unsigned int* __restrict__ ws) {
    const int chan = blockIdx.x;     // 0..95
    const int band = blockIdx.y;     // 0..16 (16 = bottom-row special band)
    const int tid  = threadIdx.x;
    const int wave  = tid >> 6;
    const int lane  = tid & 63;
    const int strip = wave >> 1;     // row group
    const int half  = wave & 1;      // x half: 0 -> [0,256), 1 -> [256,512)

    __shared__ unsigned int h[8 * 64];
    for (int i = tid; i < 512; i += 256) h[i] = 0u;
    __syncthreads();

    constexpr double Sd = 0.7071067811865476;
    constexpr double Td = 1.0 - Sd;
    const float wSS = (float)(Sd * Sd);
    const float wST = (float)(Sd * Td);
    const float wTT = (float)(Td * Td);

    const int colbase = half * 256 + lane * 4;
    const int haloCol = half ? 255 : 256;
    const size_t cb   = (size_t)chan * CH_PIX;

    unsigned long long c64 = 0ull;   // 8 bins x 8-bit counters (max 64/strip)

    auto rowpix = [&](const float4& m4, float mL, float mR,
                      const float4& d4, float dL, float dR) {
        const float cs[4]  = {m4.x, m4.y, m4.z, m4.w};
        const float es[4]  = {m4.y, m4.z, m4.w, mR};
        const float wsA[4] = {mL,   m4.x, m4.y, m4.z};
        const float ss[4]  = {d4.x, d4.y, d4.z, d4.w};
        const float sws[4] = {dL,   d4.x, d4.y, d4.z};
        const float ses[4] = {d4.y, d4.z, d4.w, dR};
        #pragma unroll
        for (int i = 0; i < 4; ++i) {
            const float c  = cs[i];
            const float tc = wTT * c;
            const float ts = wST * ss[i];
            const float nb5 = ((wST * wsA[i] + tc) + wSS * sws[i]) + ts;
            const float nb7 = ((tc + wST * es[i]) + ts) + wSS * ses[i];
            const unsigned int amt = (nb5   >= c ? 8u  : 0u)
                                   + (ss[i] >= c ? 16u : 0u)
                                   + (nb7   >= c ? 32u : 0u);
            c64 += 1ull << amt;
        }
    };

    if (band < 16) {
        const int y0 = band * 32 + strip * 16;
        const int nr = (y0 == 496) ? 15 : 16;      // rows computed here

        float4 r4[17];
        #pragma unroll
        for (int k = 0; k < 17; ++k) {
            int yy = y0 + k; yy = yy > 511 ? 511 : yy;   // clamp (safe dummy)
            r4[k] = *(const float4*)(x + cb + yy * W + colbase);
        }
        float hvAll = 0.0f;                         // 17 seam scalars, one gather
        if (lane < 17) {
            int yy = y0 + lane; yy = yy > 511 ? 511 : yy;
            hvAll = x[cb + yy * W + haloCol];
        }

        float4 m4  = r4[0];
        float2 mlr = lr_for(m4, __shfl(hvAll, 0, 64), half, lane);

        #pragma unroll
        for (int k = 0; k < 16; ++k) {
            if (k < nr) {                            // wave-uniform condition
                const float4 d4  = r4[k + 1];
                const float2 dlr = lr_for(d4, __shfl(hvAll, k + 1, 64), half, lane);
                rowpix(m4, mlr.x, mlr.y, d4, dlr.x, dlr.y);
                m4 = d4; mlr = dlr;
            }
        }
    } else if (strip == 0) {
        // bottom row y = 511: s, sw, se zero-padded
        const float4 m4 = *(const float4*)(x + cb + 511 * W + colbase);
        float hvAll = 0.0f;
        if (lane == 0) hvAll = x[cb + 511 * W + haloCol];
        const float2 mlr = lr_for(m4, __shfl(hvAll, 0, 64), half, lane);
        const float mL = mlr.x, mR = mlr.y;

        const float cs[4]  = {m4.x, m4.y, m4.z, m4.w};
        const float es[4]  = {m4.y, m4.z, m4.w, mR};
        const float wsA[4] = {mL,   m4.x, m4.y, m4.z};
        #pragma unroll
        for (int i = 0; i < 4; ++i) {
            const float c  = cs[i];
            const float tc = wTT * c;
            const float nb5 = ((wST * wsA[i] + tc) + wSS * 0.0f) + wST * 0.0f;
            const float nb7 = ((tc + wST * es[i]) + wST * 0.0f) + wSS * 0.0f;
            const unsigned int amt = (nb5  >= c ? 8u  : 0u)
                                   + (0.0f >= c ? 16u : 0u)
                                   + (nb7  >= c ? 32u : 0u);
            c64 += 1ull << amt;
        }
    }

    // merge packed byte counters into LDS histogram (8 DS atomics/thread)
    const unsigned int lo = (unsigned int)c64;
    const unsigned int hi = (unsigned int)(c64 >> 32);
    #pragma unroll
    for (int b = 0; b < 4; ++b) {
        atomicAdd(&h[(b       << 6) + lane], (lo >> (b * 8)) & 0xffu);
        atomicAdd(&h[((b + 4) << 6) + lane], (hi >> (b * 8)) & 0xffu);
    }
    __syncthreads();

    if (tid < 8) {
        unsigned int s = 0;
        #pragma unroll
        for (int l = 0; l < 64; ++l) s += h[(tid << 6) + l];
        ws[(chan * 17 + band) * 8 + tid] = s;   // non-atomic partial per block
    }
}

__global__ __launch_bounds__(64) void finalize_k(const unsigned int* __restrict__ ws,
                                                 float* __restrict__ out) {
    const int gid = blockIdx.x * 64 + threadIdx.x;   // 0..767
    if (gid < 768) {
        const int chan = gid >> 3, bin = gid & 7;
        unsigned int s = 0;
        #pragma unroll
        for (int b = 0; b < 17; ++b) s += ws[(chan * 17 + b) * 8 + bin];
        out[gid] = (float)s / 8355840.0f;   // counts / (H*W * 255/8)
    }
}

extern "C" void kernel_launch(void* const* d_in, const int* in_sizes, int n_in,
                              void* d_out, int out_size, void* d_ws, size_t ws_size,
                              hipStream_t stream) {
    const float* x = (const float*)d_in[0];
    unsigned int* wsp = (unsigned int*)d_ws;
    float* out = (float*)d_out;

    dim3 grid(96, 17);
    lbp_main_k<<<grid, 256, 0, stream>>>(x, wsp);
    finalize_k<<<12, 64, 0, stream>>>(wsp, out);
}